// Round 8
// baseline (321.345 us; speedup 1.0000x reference)
//
#include <hip/hip_runtime.h>
#include <math.h>

#define KCOMP 4
#define NN 2048
#define EE 4096
#define DD 128
#define MAXNE 96
#define MAXSE 500
#define BETA_C 0.6f
#define EPS_G 0.01f
#define LAM_S 0.05f
#define TC0_C 0.3f
#define TCMAX_C 0.7f
#define COS_EPS_C 1e-8f

typedef float vf4 __attribute__((ext_vector_type(4)));  // nt-store-compatible 16B vector

// ---- workspace layout (bytes) ----
static const size_t OFF_XHAT   = 0;          // N*D f32 = 1 MB
static const size_t OFF_XNORM  = 1048576;    // N f32 = 8 KB
static const size_t OFF_SCAL   = 1056768;    // 256 B ([12..15] gates)
static const size_t OFF_NCNT   = 1057024;    // K*N i32 = 32 KB (hipMemsetAsync before scan)
static const size_t OFF_EMASK  = 1089792;    // K*E*64 u32 = 4 MB (fully written)
static const size_t OFF_NELIST = 5284096;    // K*N*96 u16 = 1.5 MB
static const size_t OFF_IMPE   = 6856960;    // K*512 f32 = 8 KB
static const size_t OFF_EGS    = 6865152;    // K*E f32 = 64 KB
static const size_t OFF_Z      = 6930688;    // K*N f32 = 32 KB
static const size_t OFF_FEAT   = 6963456;    // K*128 f32 = 2 KB (64 used per k)
static const size_t OFF_ATT    = 6965504;    // K*128 f32 = 2 KB (64 used per k)
static const size_t OFF_FROB   = 6967552;    // K*4 f32 = 64 B

// ---------- k_scan: H scan -> emask (bitset transpose) + direct nelist append ----------
__global__ __launch_bounds__(1024) void k_scan(
    const float4* __restrict__ H4, unsigned* __restrict__ emask,
    int* __restrict__ ncnt, unsigned short* __restrict__ nelist) {
  __shared__ unsigned lds[256 * 17];       // stride-17 pad, 17,408 B
  int sb = blockIdx.x, t = threadIdx.x;
  int k = sb >> 6;
  int rem = sb & 63;
  int ch_super = rem >> 4;
  int e4_super = rem & 15;
  int chi = t >> 6;                        // [0,16)
  int e4i = t & 63;                        // [0,64)
  int ch = ch_super * 16 + chi;
  int e4 = e4_super * 64 + e4i;
  int n0 = ch * 32;
  const float4* p = H4 + ((size_t)(k * NN + n0)) * (EE / 4) + e4;
  unsigned w0 = 0, w1b = 0, w2b = 0, w3 = 0;
  for (int rb = 0; rb < 32; rb += 8) {
    float4 v[8];
#pragma unroll
    for (int u = 0; u < 8; ++u) v[u] = p[(size_t)(rb + u) * (EE / 4)];
#pragma unroll
    for (int u = 0; u < 8; ++u) {
      unsigned bit = 1u << (rb + u);
      w0  |= (v[u].x > 0.f) ? bit : 0u;
      w1b |= (v[u].y > 0.f) ? bit : 0u;
      w2b |= (v[u].z > 0.f) ? bit : 0u;
      w3  |= (v[u].w > 0.f) ? bit : 0u;
    }
  }
  int el = e4i * 4;
  lds[(el + 0) * 17 + chi] = w0;
  lds[(el + 1) * 17 + chi] = w1b;
  lds[(el + 2) * 17 + chi] = w2b;
  lds[(el + 3) * 17 + chi] = w3;
  // --- direct append: ~1 hit per thread (density 0.008 x 128 bits) ---
  {
    int ebase = e4 * 4;
    unsigned ws[4] = {w0, w1b, w2b, w3};
#pragma unroll
    for (int j = 0; j < 4; ++j) {
      unsigned wd = ws[j];
      while (wd) {
        int bit = __builtin_ctz(wd); wd &= wd - 1;
        int node = n0 + bit;
        int slot = atomicAdd(&ncnt[k * NN + node], 1);
        if (slot < MAXNE)
          nelist[((size_t)(k * NN + node)) * MAXNE + slot] =
              (unsigned short)(ebase + j);
      }
    }
  }
  __syncthreads();
  int e_base = e4_super * 256;
  int wi = t & 15;
  int eo = t >> 4;                         // [0,64)
#pragma unroll
  for (int it = 0; it < 4; ++it) {
    int e_local = it * 64 + eo;
    emask[((size_t)(k * EE) + e_base + e_local) * 64 + ch_super * 16 + wi] =
        lds[e_local * 17 + wi];
  }
}

// ---------- k_mlp: MLP chain, 32 nodes/block (64 blocks/k), 4 rows/thread ----------
__global__ __launch_bounds__(1024) void k_mlp(
    const float* __restrict__ X,
    const float* __restrict__ w1, const float* __restrict__ b1,
    const float* __restrict__ w2, const float* __restrict__ b2,
    const float* __restrict__ aw1, const float* __restrict__ ab1,
    const float* __restrict__ aw2, const float* __restrict__ ab2,
    float* __restrict__ featA, float* __restrict__ attA) {
  __shared__ float smem[8224];   // 32,896 B
  int b = blockIdx.x, t = threadIdx.x;
  int k = b >> 6;
  int bx = b & 63;
  float* Xs  = smem;                     // [32][128] (XKs aliases after s1)
  float* H1s = smem + 4096;              // [32][128] (A1s aliases)
  float* A1s = H1s;                      // [32][64] (alias)
  float* red = smem + 8192;              // 32
  int n0 = bx * 32;
  for (int i = t; i < 32 * 128; i += 1024) Xs[i] = X[(size_t)n0 * 128 + i];
  __syncthreads();

  int h = t & 127, g = t >> 7;           // g in [0,8): rows 4g..4g+3
  const float* W1 = w1 + (size_t)k * 128 * 128;
  float acc[4];
  {
    float bb = b1[k * 128 + h];
#pragma unroll
    for (int rr = 0; rr < 4; ++rr) acc[rr] = bb;
  }
  for (int d = 0; d < 128; d += 4) {
    float wa = W1[(d + 0) * 128 + h];
    float wb = W1[(d + 1) * 128 + h];
    float wc = W1[(d + 2) * 128 + h];
    float wd2 = W1[(d + 3) * 128 + h];
#pragma unroll
    for (int rr = 0; rr < 4; ++rr) {
      float4 x = *(const float4*)&Xs[(g * 4 + rr) * 128 + d];
      acc[rr] = fmaf(x.x, wa, acc[rr]); acc[rr] = fmaf(x.y, wb, acc[rr]);
      acc[rr] = fmaf(x.z, wc, acc[rr]); acc[rr] = fmaf(x.w, wd2, acc[rr]);
    }
  }
#pragma unroll
  for (int rr = 0; rr < 4; ++rr) H1s[(g * 4 + rr) * 128 + h] = fmaxf(acc[rr], 0.f);
  __syncthreads();

  const float* W2 = w2 + (size_t)k * 128 * 128;
  {
    float bb = b2[k * 128 + h];
#pragma unroll
    for (int rr = 0; rr < 4; ++rr) acc[rr] = bb;
  }
  for (int d = 0; d < 128; d += 4) {
    float wa = W2[(d + 0) * 128 + h];
    float wb = W2[(d + 1) * 128 + h];
    float wc = W2[(d + 2) * 128 + h];
    float wd2 = W2[(d + 3) * 128 + h];
#pragma unroll
    for (int rr = 0; rr < 4; ++rr) {
      float4 x = *(const float4*)&H1s[(g * 4 + rr) * 128 + d];
      acc[rr] = fmaf(x.x, wa, acc[rr]); acc[rr] = fmaf(x.y, wb, acc[rr]);
      acc[rr] = fmaf(x.z, wc, acc[rr]); acc[rr] = fmaf(x.w, wd2, acc[rr]);
    }
  }
  float fpart = 0.f;
  __syncthreads();
#pragma unroll
  for (int rr = 0; rr < 4; ++rr) {
    Xs[(g * 4 + rr) * 128 + h] = acc[rr];          // XKs aliases Xs (Xs dead)
    fpart = fmaf(acc[rr], acc[rr], fpart);
  }
  __syncthreads();

  // att1: 2 rows/thread
  int h2 = t & 63, g4 = t >> 6;
  const float* AW1 = aw1 + (size_t)k * 128 * 64;
  float a2[2];
  {
    float ab = ab1[k * 64 + h2];
    a2[0] = ab; a2[1] = ab;
  }
  for (int d = 0; d < 128; d += 4) {
    float wa = AW1[(d + 0) * 64 + h2];
    float wb = AW1[(d + 1) * 64 + h2];
    float wc = AW1[(d + 2) * 64 + h2];
    float wd2 = AW1[(d + 3) * 64 + h2];
#pragma unroll
    for (int q = 0; q < 2; ++q) {
      float4 x = *(const float4*)&Xs[(g4 * 2 + q) * 128 + d];
      a2[q] = fmaf(x.x, wa, a2[q]); a2[q] = fmaf(x.y, wb, a2[q]);
      a2[q] = fmaf(x.z, wc, a2[q]); a2[q] = fmaf(x.w, wd2, a2[q]);
    }
  }
  __syncthreads();
#pragma unroll
  for (int q = 0; q < 2; ++q) A1s[(g4 * 2 + q) * 64 + h2] = fmaxf(a2[q], 0.f);
  __syncthreads();

  float attsum = 0.f;
  if (t < 32) {
    const float* AW2 = aw2 + (size_t)k * 64;
    float a = ab2[k];
    for (int d = 0; d < 64; d += 4) {
      float4 av = *(const float4*)&A1s[t * 64 + d];
      a = fmaf(av.x, AW2[d + 0], a);
      a = fmaf(av.y, AW2[d + 1], a);
      a = fmaf(av.z, AW2[d + 2], a);
      a = fmaf(av.w, AW2[d + 3], a);
    }
    attsum = 1.f / (1.f + expf(-a));
  }
  for (int o = 32; o > 0; o >>= 1) {
    fpart  += __shfl_xor(fpart, o, 64);
    attsum += __shfl_xor(attsum, o, 64);
  }
  int wv = t >> 6, ln = t & 63;
  if (ln == 0) { red[wv] = fpart; red[16 + wv] = attsum; }
  __syncthreads();
  if (t == 0) {
    float fs = 0.f, as = 0.f;
#pragma unroll
    for (int i = 0; i < 16; i++) { fs += red[i]; as += red[16 + i]; }
    featA[k * 128 + bx] = fs;
    attA[k * 128 + bx]  = as;
  }
}

// ---------- k_xfr: xhat/xnorm (blocks [0,128)) + frobenius partials ([128,144)) ----------
__global__ __launch_bounds__(1024) void k_xfr(
    const float* __restrict__ X, float* __restrict__ xhat, float* __restrict__ xnorm,
    const float4* __restrict__ compW4, float* __restrict__ frobA) {
  __shared__ float red[16];
  int b = blockIdx.x, t = threadIdx.x;
  if (b < 128) {
    int node = b * 16 + (t >> 6);
    int lane = t & 63;
    float2 v = ((const float2*)X)[(size_t)node * 64 + lane];
    float ss = v.x * v.x + v.y * v.y;
    for (int o = 32; o > 0; o >>= 1) ss += __shfl_xor(ss, o, 64);
    float nrm = sqrtf(ss);
    float den = fmaxf(nrm, COS_EPS_C);
    if (lane == 0) xnorm[node] = nrm;
    float2 o2; o2.x = v.x / den; o2.y = v.y / den;
    ((float2*)xhat)[(size_t)node * 64 + lane] = o2;
    return;
  }
  int fb = b - 128;
  int k = fb >> 2, idx = fb & 3;
  float4 v = compW4[(size_t)k * 4096 + idx * 1024 + t];
  float s = v.x * v.x + v.y * v.y + v.z * v.z + v.w * v.w;
  for (int o = 32; o > 0; o >>= 1) s += __shfl_xor(s, o, 64);
  int wv = t >> 6, ln = t & 63;
  if (ln == 0) red[wv] = s;
  __syncthreads();
  if (t == 0) {
    float fs = 0.f;
#pragma unroll
    for (int i = 0; i < 16; i++) fs += red[i];
    frobA[k * 4 + idx] = fs;
  }
}

// ---------- k_d2: cosine importance (wave per edge, e<500) ----------
__global__ void k_d2(const unsigned* __restrict__ emask, const float* __restrict__ xhat,
                     float* __restrict__ impE) {
  int t = threadIdx.x;
  int k = blockIdx.y;
  int bx = blockIdx.x;
  int e = bx * 4 + (t >> 6);
  int lane = t & 63;
  unsigned w = emask[((size_t)(k * EE) + e) * 64 + lane];
  int pc = __popc(w);
  for (int o = 32; o > 0; o >>= 1) pc += __shfl_xor(pc, o, 64);
  float impv = 0.1f;
  if (pc >= 2) {
    unsigned l1 = w ? (unsigned)((lane << 5) + __builtin_ctz(w)) : 0xffffffffu;
    unsigned wr = w & (w - 1);
    unsigned l2 = wr ? (unsigned)((lane << 5) + __builtin_ctz(wr)) : 0xffffffffu;
    unsigned g1 = l1;
    for (int o = 32; o > 0; o >>= 1) {
      unsigned x = (unsigned)__shfl_xor((int)g1, o, 64);
      g1 = g1 < x ? g1 : x;
    }
    unsigned cand = (l1 == g1) ? l2 : l1;
    unsigned g2 = cand;
    for (int o = 32; o > 0; o >>= 1) {
      unsigned x = (unsigned)__shfl_xor((int)g2, o, 64);
      g2 = g2 < x ? g2 : x;
    }
    float2 xi = ((const float2*)xhat)[(size_t)g1 * 64 + lane];
    float2 xj = ((const float2*)xhat)[(size_t)g2 * 64 + lane];
    float d = xi.x * xj.x + xi.y * xj.y;
    for (int o = 32; o > 0; o >>= 1) d += __shfl_xor(d, o, 64);
    impv = d;
  }
  if (lane == 0) impE[k * 512 + e] = impv;
}

// ---------- k_edgegate: edge softmax + gating ----------
__device__ __forceinline__ float blockReduceSum16(float v, float* red, int t) {
  for (int o = 32; o > 0; o >>= 1) v += __shfl_xor(v, o, 64);
  __syncthreads();
  if ((t & 63) == 0) red[t >> 6] = v;
  __syncthreads();
  float s = red[0];
#pragma unroll
  for (int i = 1; i < 16; i++) s += red[i];
  return s;
}

__global__ void k_edgegate(const float* __restrict__ impE,
                           const float* __restrict__ featA, const float* __restrict__ attA,
                           const float* __restrict__ frobA, float* __restrict__ scal,
                           const int* __restrict__ epoch, float* __restrict__ out_gates,
                           float* __restrict__ egscaled, float* __restrict__ out_eg) {
  __shared__ float red[16];
  __shared__ int redi[16];
  __shared__ float imps[KCOMP];
  int k = blockIdx.x;
  int t = threadIdx.x;
  int wv0 = t >> 6, ln0 = t & 63;
  if (wv0 < KCOMP) {
    float pf = featA[wv0 * 128 + ln0];
    float pa = attA[wv0 * 128 + ln0];
    float pr = (ln0 < 4) ? frobA[wv0 * 4 + ln0] : 0.f;
    for (int o = 32; o > 0; o >>= 1) {
      pf += __shfl_xor(pf, o, 64);
      pa += __shfl_xor(pa, o, 64);
      pr += __shfl_xor(pr, o, 64);
    }
    if (ln0 == 0)
      imps[wv0] = BETA_C * sqrtf(pr) * sqrtf(pf) + (1.f - BETA_C) * (pa / (float)NN);
  }
  __syncthreads();
  float gates[KCOMP];
  float tc;
  {
    float mx = imps[0];
    for (int kk = 1; kk < KCOMP; kk++) mx = fmaxf(mx, imps[kk]);
    float ex[KCOMP], ssum = 0.f;
    for (int kk = 0; kk < KCOMP; kk++) { ex[kk] = expf(imps[kk] - mx); ssum += ex[kk]; }
    tc = TC0_C + (1.f - expf(-LAM_S * (float)epoch[0])) * (TCMAX_C - TC0_C);
    for (int kk = 0; kk < KCOMP; kk++) {
      float pi = ex[kk] / ssum;
      gates[kk] = fminf(fmaxf((pi - tc) / EPS_G + 0.5f, 0.f), 1.f);
    }
    int am = 0; float bv2 = gates[0];
    for (int kk = 1; kk < KCOMP; kk++) if (gates[kk] > bv2) { bv2 = gates[kk]; am = kk; }
    gates[am] = fmaxf(gates[am], 1.f);
  }
  if (t == 0) {
    scal[12 + k] = gates[k];
    if (k == 0) for (int kk = 0; kk < KCOMP; kk++) out_gates[kk] = gates[kk];
  }
  float imp[4];
#pragma unroll
  for (int j = 0; j < 4; j++) {
    int e = t + j * 1024;
    imp[j] = (e < MAXSE) ? impE[k * 512 + e] : 0.f;
  }
  float m = fmaxf(fmaxf(imp[0], imp[1]), fmaxf(imp[2], imp[3]));
  for (int o = 32; o > 0; o >>= 1) m = fmaxf(m, __shfl_xor(m, o, 64));
  __syncthreads();
  if ((t & 63) == 0) red[t >> 6] = m;
  __syncthreads();
  m = red[0];
#pragma unroll
  for (int i = 1; i < 16; i++) m = fmaxf(m, red[i]);
  float p[4], psum = 0.f;
#pragma unroll
  for (int j = 0; j < 4; j++) { p[j] = expf(imp[j] - m); psum += p[j]; }
  float S = blockReduceSum16(psum, red, t);
  float pi[4], tot = 0.f;
#pragma unroll
  for (int j = 0; j < 4; j++) { pi[j] = p[j] / S; tot += pi[j]; }
  float T = blockReduceSum16(tot, red, t);
  float mean = T / (float)EE;
  float devs = 0.f;
#pragma unroll
  for (int j = 0; j < 4; j++) { float d = pi[j] - mean; devs = fmaf(d, d, devs); }
  float V = blockReduceSum16(devs, red, t);
  float stdv = sqrtf(V / (float)(EE - 1));
  float theta = fminf(tc, mean + stdv);
  float eg[4], egsum = 0.f;
#pragma unroll
  for (int j = 0; j < 4; j++) {
    eg[j] = fminf(fmaxf((pi[j] - theta) / EPS_G + 0.5f, 0.f), 1.f);
    egsum += eg[j];
  }
  float EGS = blockReduceSum16(egsum, red, t);
  float bv = -1e30f; int bi = 0x7fffffff;
#pragma unroll
  for (int j = 0; j < 4; j++) if (pi[j] > bv) { bv = pi[j]; bi = t + j * 1024; }
  for (int o = 32; o > 0; o >>= 1) {
    float ov = __shfl_xor(bv, o, 64); int oi = __shfl_xor(bi, o, 64);
    if (ov > bv || (ov == bv && oi < bi)) { bv = ov; bi = oi; }
  }
  __syncthreads();
  if ((t & 63) == 0) { red[t >> 6] = bv; redi[t >> 6] = bi; }
  __syncthreads();
  float abv = red[0]; int abi = redi[0];
#pragma unroll
  for (int i = 1; i < 16; i++) {
    float ov = red[i]; int oi = redi[i];
    if (ov > abv || (ov == abv && oi < abi)) { abv = ov; abi = oi; }
  }
  float g = gates[k];
#pragma unroll
  for (int j = 0; j < 4; j++) {
    int e = t + j * 1024;
    float egv = eg[j];
    if (EGS < 1.f && e == abi) egv = 1.f;
    out_eg[(size_t)k * EE + e] = egv;
    float eff = (g > 0.5f) ? egv : 1.f;
    egscaled[k * EE + e] = g * eff;
  }
}

// ---------- k_hprow: Hp row compose directly in global (no LDS row) + rowscan ----------
__global__ void k_hprow(const unsigned* __restrict__ emask,
                        const int* __restrict__ ncnt, const unsigned short* __restrict__ nelist,
                        const float* __restrict__ egs, const float* __restrict__ scal,
                        const float* __restrict__ xhat, const float* __restrict__ xnorm,
                        float* __restrict__ out, float* __restrict__ z) {
  __shared__ unsigned short elds[MAXNE];
  __shared__ float evals[MAXNE];
  __shared__ unsigned wpart[4][64];
  __shared__ unsigned short list[2048];
  __shared__ int cnt_s;
  __shared__ float sred[4];
  int k = blockIdx.y, n = blockIdx.x, t = threadIdx.x;
  float g = scal[12 + k];
  float* orow = out + ((size_t)(k * NN + n)) * EE;
  vf4* o4 = (vf4*)orow;
  vf4 z4 = {0.f, 0.f, 0.f, 0.f};
  if (g <= 0.f) {
#pragma unroll
    for (int i = 0; i < 4; i++) __builtin_nontemporal_store(z4, &o4[t + i * 256]);
    if (t == 0) z[k * NN + n] = 0.f;
    return;
  }
  int ec = ncnt[k * NN + n]; if (ec > MAXNE) ec = MAXNE;
  if (t == 0) cnt_s = 0;
  if (t < ec) {
    int e = nelist[((size_t)(k * NN + n)) * MAXNE + t];
    elds[t] = (unsigned short)e;
    evals[t] = egs[k * EE + e];
  }
  // zero the full output row straight to global (write-once data, nt)
#pragma unroll
  for (int i = 0; i < 4; i++) __builtin_nontemporal_store(z4, &o4[t + i * 256]);
  __syncthreads();   // drains vmcnt: zeros globally ordered before scatter below
  if (t < ec) orow[elds[t]] = evals[t];
  // ---- rowscan (uses evals in LDS; no row buffer needed) ----
  int lane = t & 63, wv = t >> 6;
  unsigned acc = 0;
  for (int it = wv; it < ec; it += 4) {
    if (evals[it] > 0.f) acc |= emask[((size_t)(k * EE) + elds[it]) * 64 + lane];
  }
  wpart[wv][lane] = acc;
  __syncthreads();
  if (t < 64) {
    unsigned w = wpart[0][t] | wpart[1][t] | wpart[2][t] | wpart[3][t];
    if (t == (n >> 5)) w &= ~(1u << (n & 31));
    int c = __popc(w);
    if (c > 0) {
      int base = atomicAdd(&cnt_s, c);
      while (w) {
        int b = __builtin_ctz(w); w &= w - 1;
        list[base++] = (unsigned short)((t << 5) + b);
      }
    }
  }
  __syncthreads();
  int cnt = cnt_s;
  if (cnt == 0) { if (t == 0) z[k * NN + n] = 0.f; return; }
  int fc = lane & 31, hh = lane >> 5;
  float4 xn4 = ((const float4*)xhat)[(size_t)n * 32 + fc];
  float a = 0.f;
#pragma unroll 4
  for (int it = wv * 2 + hh; it < cnt; it += 8) {
    int m = (int)list[it];
    float4 xm = ((const float4*)xhat)[(size_t)m * 32 + fc];
    a += xn4.x * xm.x + xn4.y * xm.y + xn4.z * xm.z + xn4.w * xm.w;
  }
  for (int o = 32; o > 0; o >>= 1) a += __shfl_xor(a, o, 64);
  if (lane == 0) sred[wv] = a;
  __syncthreads();
  if (t == 0) {
    float s = sred[0] + sred[1] + sred[2] + sred[3];
    z[k * NN + n] = (s / (float)cnt) * xnorm[n];
  }
}

// ---------- k_npi: npi = softmax(z) per k ----------
__global__ void k_npi(const float* __restrict__ z, float* __restrict__ out_npi) {
  __shared__ float red[4];
  int k = blockIdx.x, t = threadIdx.x;
  float v[8]; float m = -1e30f;
#pragma unroll
  for (int j = 0; j < 8; j++) { v[j] = z[k * NN + t + j * 256]; m = fmaxf(m, v[j]); }
  for (int o = 32; o > 0; o >>= 1) m = fmaxf(m, __shfl_xor(m, o, 64));
  if ((t & 63) == 0) red[t >> 6] = m;
  __syncthreads();
  m = fmaxf(fmaxf(red[0], red[1]), fmaxf(red[2], red[3]));
  __syncthreads();
  float pe[8]; float s = 0.f;
#pragma unroll
  for (int j = 0; j < 8; j++) { pe[j] = expf(v[j] - m); s += pe[j]; }
  for (int o = 32; o > 0; o >>= 1) s += __shfl_xor(s, o, 64);
  if ((t & 63) == 0) red[t >> 6] = s;
  __syncthreads();
  s = red[0] + red[1] + red[2] + red[3];
#pragma unroll
  for (int j = 0; j < 8; j++) out_npi[k * NN + t + j * 256] = pe[j] / s;
}

extern "C" void kernel_launch(void* const* d_in, const int* in_sizes, int n_in,
                              void* d_out, int out_size, void* d_ws, size_t ws_size,
                              hipStream_t stream) {
  const float* H     = (const float*)d_in[0];
  const float* X     = (const float*)d_in[1];
  const int*   epoch = (const int*)d_in[2];
  const float* w1    = (const float*)d_in[3];
  const float* b1    = (const float*)d_in[4];
  const float* w2    = (const float*)d_in[5];
  const float* b2    = (const float*)d_in[6];
  const float* compW = (const float*)d_in[7];
  const float* aw1   = (const float*)d_in[8];
  const float* ab1   = (const float*)d_in[9];
  const float* aw2   = (const float*)d_in[10];
  const float* ab2   = (const float*)d_in[11];

  char* ws = (char*)d_ws;
  float* xhat  = (float*)(ws + OFF_XHAT);
  float* xnorm = (float*)(ws + OFF_XNORM);
  float* scal  = (float*)(ws + OFF_SCAL);
  int*   ncnt  = (int*)(ws + OFF_NCNT);
  unsigned* emask = (unsigned*)(ws + OFF_EMASK);
  unsigned short* nelist = (unsigned short*)(ws + OFF_NELIST);
  float* impE  = (float*)(ws + OFF_IMPE);
  float* egs   = (float*)(ws + OFF_EGS);
  float* zbuf  = (float*)(ws + OFF_Z);
  float* featA = (float*)(ws + OFF_FEAT);
  float* attA  = (float*)(ws + OFF_ATT);
  float* frobA = (float*)(ws + OFF_FROB);

  float* out       = (float*)d_out;
  float* out_gates = out + (size_t)KCOMP * NN * EE;
  float* out_eg    = out_gates + KCOMP;
  float* out_npi   = out_eg + (size_t)KCOMP * EE;

  hipMemsetAsync(ncnt, 0, (size_t)KCOMP * NN * sizeof(int), stream);
  k_scan<<<256, 1024, 0, stream>>>((const float4*)H, emask, ncnt, nelist);
  k_mlp<<<256, 1024, 0, stream>>>(X, w1, b1, w2, b2, aw1, ab1, aw2, ab2, featA, attA);
  k_xfr<<<144, 1024, 0, stream>>>(X, xhat, xnorm, (const float4*)compW, frobA);
  k_d2<<<dim3(125, KCOMP), 256, 0, stream>>>(emask, xhat, impE);
  k_edgegate<<<KCOMP, 1024, 0, stream>>>(impE, featA, attA, frobA, scal, epoch,
                                         out_gates, egs, out_eg);
  k_hprow<<<dim3(NN, KCOMP), 256, 0, stream>>>(emask, ncnt, nelist, egs, scal, xhat, xnorm,
                                               out, zbuf);
  k_npi<<<KCOMP, 256, 0, stream>>>(zbuf, out_npi);
}

// Round 9
// 299.084 us; speedup vs baseline: 1.0744x; 1.0744x over previous
//
#include <hip/hip_runtime.h>
#include <math.h>

#define KCOMP 4
#define NN 2048
#define EE 4096
#define DD 128
#define MAXNE 96
#define MAXSE 500
#define BETA_C 0.6f
#define EPS_G 0.01f
#define LAM_S 0.05f
#define TC0_C 0.3f
#define TCMAX_C 0.7f
#define COS_EPS_C 1e-8f

typedef float vf4 __attribute__((ext_vector_type(4)));  // nt-store-compatible 16B vector

// ---- workspace layout (bytes) ----
static const size_t OFF_XHAT   = 0;          // N*D f32 = 1 MB
static const size_t OFF_XNORM  = 1048576;    // N f32 = 8 KB
static const size_t OFF_SCAL   = 1056768;    // 256 B ([12..15] gates)
static const size_t OFF_NCNT   = 1057024;    // K*N i32 = 32 KB (hipMemsetAsync before d1)
static const size_t OFF_EMASK  = 1089792;    // K*E*64 u32 = 4 MB (fully written)
static const size_t OFF_NELIST = 5284096;    // K*N*96 u16 = 1.5 MB
static const size_t OFF_IMPE   = 6856960;    // K*512 f32 = 8 KB
static const size_t OFF_EGS    = 6865152;    // K*E f32 = 64 KB
static const size_t OFF_Z      = 6930688;    // K*N f32 = 32 KB
static const size_t OFF_FEAT   = 6963456;    // K*128 f32 = 2 KB (32 used per k)
static const size_t OFF_ATT    = 6965504;    // K*128 f32 = 2 KB (32 used per k)
static const size_t OFF_FROB   = 6967552;    // K*4 f32 = 64 B

// ---------- dispatch 1: MLP (64-node blocks) + H scan (emask + direct nelist append)
//            + xhat + frobW ----------
// blocks [0,128): MLP; [128,384): H scan; [384,512): xhat; [512,528): frobW
__global__ __launch_bounds__(1024) void k_d1(
    const float4* __restrict__ H4, unsigned* __restrict__ emask,
    const float* __restrict__ X, float* __restrict__ xhat, float* __restrict__ xnorm,
    const float* __restrict__ w1, const float* __restrict__ b1,
    const float* __restrict__ w2, const float* __restrict__ b2,
    const float* __restrict__ aw1, const float* __restrict__ ab1,
    const float* __restrict__ aw2, const float* __restrict__ ab2,
    const float4* __restrict__ compW4, int* __restrict__ ncnt,
    unsigned short* __restrict__ nelist,
    float* __restrict__ featA, float* __restrict__ attA, float* __restrict__ frobA) {
  __shared__ float smem[16416];   // 65,664 B -> 2 blocks/CU (wave-capped)
  int b = blockIdx.x, t = threadIdx.x;
  if (b < 128) {
    // --- MLP chain, 64 nodes/block, 8 rows/thread ---
    int k = b >> 5;                        // 32 blocks per k
    int bx = b & 31;
    float* Xs  = smem;                     // [64][128] 32 KB (XKs aliases after s1)
    float* H1s = smem + 8192;              // [64][128] 32 KB (A1s aliases)
    float* A1s = H1s;                      // [64][64]  16 KB (alias)
    float* red = smem + 16384;             // 32
    int n0 = bx * 64;
    for (int i = t; i < 64 * 128; i += 1024) Xs[i] = X[(size_t)n0 * 128 + i];
    __syncthreads();

    int h = t & 127, g = t >> 7;           // g in [0,8): rows 8g..8g+7
    const float* W1 = w1 + (size_t)k * 128 * 128;
    float acc[8];
    {
      float bb = b1[k * 128 + h];
#pragma unroll
      for (int rr = 0; rr < 8; ++rr) acc[rr] = bb;
    }
    for (int d = 0; d < 128; d += 4) {
      float wa = W1[(d + 0) * 128 + h];
      float wb = W1[(d + 1) * 128 + h];
      float wc = W1[(d + 2) * 128 + h];
      float wd2 = W1[(d + 3) * 128 + h];
#pragma unroll
      for (int rr = 0; rr < 8; ++rr) {
        float4 x = *(const float4*)&Xs[(g * 8 + rr) * 128 + d];
        acc[rr] = fmaf(x.x, wa, acc[rr]); acc[rr] = fmaf(x.y, wb, acc[rr]);
        acc[rr] = fmaf(x.z, wc, acc[rr]); acc[rr] = fmaf(x.w, wd2, acc[rr]);
      }
    }
#pragma unroll
    for (int rr = 0; rr < 8; ++rr) H1s[(g * 8 + rr) * 128 + h] = fmaxf(acc[rr], 0.f);
    __syncthreads();

    const float* W2 = w2 + (size_t)k * 128 * 128;
    {
      float bb = b2[k * 128 + h];
#pragma unroll
      for (int rr = 0; rr < 8; ++rr) acc[rr] = bb;
    }
    for (int d = 0; d < 128; d += 4) {
      float wa = W2[(d + 0) * 128 + h];
      float wb = W2[(d + 1) * 128 + h];
      float wc = W2[(d + 2) * 128 + h];
      float wd2 = W2[(d + 3) * 128 + h];
#pragma unroll
      for (int rr = 0; rr < 8; ++rr) {
        float4 x = *(const float4*)&H1s[(g * 8 + rr) * 128 + d];
        acc[rr] = fmaf(x.x, wa, acc[rr]); acc[rr] = fmaf(x.y, wb, acc[rr]);
        acc[rr] = fmaf(x.z, wc, acc[rr]); acc[rr] = fmaf(x.w, wd2, acc[rr]);
      }
    }
    float fpart = 0.f;
    __syncthreads();                       // all H1s reads done before later A1s writes
#pragma unroll
    for (int rr = 0; rr < 8; ++rr) {
      Xs[(g * 8 + rr) * 128 + h] = acc[rr];          // XKs aliases Xs (Xs dead)
      fpart = fmaf(acc[rr], acc[rr], fpart);
    }
    __syncthreads();

    // att1: 4 rows/thread
    int h2 = t & 63, g4 = t >> 6;
    const float* AW1 = aw1 + (size_t)k * 128 * 64;
    float a4[4];
    {
      float ab = ab1[k * 64 + h2];
#pragma unroll
      for (int q = 0; q < 4; ++q) a4[q] = ab;
    }
    for (int d = 0; d < 128; d += 4) {
      float wa = AW1[(d + 0) * 64 + h2];
      float wb = AW1[(d + 1) * 64 + h2];
      float wc = AW1[(d + 2) * 64 + h2];
      float wd2 = AW1[(d + 3) * 64 + h2];
#pragma unroll
      for (int q = 0; q < 4; ++q) {
        float4 x = *(const float4*)&Xs[(g4 * 4 + q) * 128 + d];
        a4[q] = fmaf(x.x, wa, a4[q]); a4[q] = fmaf(x.y, wb, a4[q]);
        a4[q] = fmaf(x.z, wc, a4[q]); a4[q] = fmaf(x.w, wd2, a4[q]);
      }
    }
    __syncthreads();                       // H1s (=A1s region) fully dead
#pragma unroll
    for (int q = 0; q < 4; ++q) A1s[(g4 * 4 + q) * 64 + h2] = fmaxf(a4[q], 0.f);
    __syncthreads();

    float attsum = 0.f;
    if (t < 64) {
      const float* AW2 = aw2 + (size_t)k * 64;
      float a = ab2[k];
      for (int d = 0; d < 64; d += 4) {
        float4 av = *(const float4*)&A1s[t * 64 + d];
        a = fmaf(av.x, AW2[d + 0], a);
        a = fmaf(av.y, AW2[d + 1], a);
        a = fmaf(av.z, AW2[d + 2], a);
        a = fmaf(av.w, AW2[d + 3], a);
      }
      attsum = 1.f / (1.f + expf(-a));
    }
    for (int o = 32; o > 0; o >>= 1) {
      fpart  += __shfl_xor(fpart, o, 64);
      attsum += __shfl_xor(attsum, o, 64);
    }
    int wv = t >> 6, ln = t & 63;
    if (ln == 0) { red[wv] = fpart; red[16 + wv] = attsum; }
    __syncthreads();
    if (t == 0) {
      float fs = 0.f, as = 0.f;
#pragma unroll
      for (int i = 0; i < 16; i++) { fs += red[i]; as += red[16 + i]; }
      featA[k * 128 + bx] = fs;
      attA[k * 128 + bx]  = as;
    }
    return;
  }
  if (b < 384) {
    // --- H scan: bitset transpose (emask) + direct nelist append from registers ---
    unsigned* lds = (unsigned*)smem;       // [256][17] stride-17 pad (17,408 B)
    int sb = b - 128;
    int k = sb >> 6;
    int rem = sb & 63;
    int ch_super = rem >> 4;
    int e4_super = rem & 15;
    int chi = t >> 6;                      // [0,16)
    int e4i = t & 63;                      // [0,64)
    int ch = ch_super * 16 + chi;
    int e4 = e4_super * 64 + e4i;
    int n0 = ch * 32;
    const float4* p = H4 + ((size_t)(k * NN + n0)) * (EE / 4) + e4;
    unsigned w0 = 0, w1b = 0, w2b = 0, w3 = 0;
    for (int rb = 0; rb < 32; rb += 8) {
      float4 v[8];
#pragma unroll
      for (int u = 0; u < 8; ++u) v[u] = p[(size_t)(rb + u) * (EE / 4)];
#pragma unroll
      for (int u = 0; u < 8; ++u) {
        unsigned bit = 1u << (rb + u);
        w0  |= (v[u].x > 0.f) ? bit : 0u;
        w1b |= (v[u].y > 0.f) ? bit : 0u;
        w2b |= (v[u].z > 0.f) ? bit : 0u;
        w3  |= (v[u].w > 0.f) ? bit : 0u;
      }
    }
    int el = e4i * 4;
    lds[(el + 0) * 17 + chi] = w0;
    lds[(el + 1) * 17 + chi] = w1b;
    lds[(el + 2) * 17 + chi] = w2b;
    lds[(el + 3) * 17 + chi] = w3;
    // --- direct append: ~1 hit per thread (density 0.008 x 128 bits) ---
    {
      int ebase = e4 * 4;
      unsigned ws[4] = {w0, w1b, w2b, w3};
#pragma unroll
      for (int j = 0; j < 4; ++j) {
        unsigned wd = ws[j];
        while (wd) {
          int bit = __builtin_ctz(wd); wd &= wd - 1;
          int node = n0 + bit;
          int slot = atomicAdd(&ncnt[k * NN + node], 1);
          if (slot < MAXNE)
            nelist[((size_t)(k * NN + node)) * MAXNE + slot] =
                (unsigned short)(ebase + j);
        }
      }
    }
    __syncthreads();
    int e_base = e4_super * 256;
    int wi = t & 15;
    int eo = t >> 4;                       // [0,64)
#pragma unroll
    for (int it = 0; it < 4; ++it) {
      int e_local = it * 64 + eo;
      emask[((size_t)(k * EE) + e_base + e_local) * 64 + ch_super * 16 + wi] =
          lds[e_local * 17 + wi];
    }
    return;
  }
  if (b < 512) {
    // --- xhat / xnorm ---
    int xb = b - 384;
    int node = xb * 16 + (t >> 6);
    int lane = t & 63;
    float2 v = ((const float2*)X)[(size_t)node * 64 + lane];
    float ss = v.x * v.x + v.y * v.y;
    for (int o = 32; o > 0; o >>= 1) ss += __shfl_xor(ss, o, 64);
    float nrm = sqrtf(ss);
    float den = fmaxf(nrm, COS_EPS_C);
    if (lane == 0) xnorm[node] = nrm;
    float2 o2; o2.x = v.x / den; o2.y = v.y / den;
    ((float2*)xhat)[(size_t)node * 64 + lane] = o2;
    return;
  }
  // --- frobenius^2 partials of compW: 4 blocks per k ---
  {
    int fb = b - 512;
    int k = fb >> 2, idx = fb & 3;
    float* red = smem;
    float4 v = compW4[(size_t)k * 4096 + idx * 1024 + t];
    float s = v.x * v.x + v.y * v.y + v.z * v.z + v.w * v.w;
    for (int o = 32; o > 0; o >>= 1) s += __shfl_xor(s, o, 64);
    int wv = t >> 6, ln = t & 63;
    if (ln == 0) red[wv] = s;
    __syncthreads();
    if (t == 0) {
      float fs = 0.f;
#pragma unroll
      for (int i = 0; i < 16; i++) fs += red[i];
      frobA[k * 4 + idx] = fs;
    }
  }
}

// ---------- dispatch 2: cosine importance only (wave per edge, e<500) ----------
__global__ void k_d2(const unsigned* __restrict__ emask, const float* __restrict__ xhat,
                     float* __restrict__ impE) {
  int t = threadIdx.x;
  int k = blockIdx.y;
  int bx = blockIdx.x;
  int e = bx * 4 + (t >> 6);
  int lane = t & 63;
  unsigned w = emask[((size_t)(k * EE) + e) * 64 + lane];
  int pc = __popc(w);
  for (int o = 32; o > 0; o >>= 1) pc += __shfl_xor(pc, o, 64);
  float impv = 0.1f;
  if (pc >= 2) {
    unsigned l1 = w ? (unsigned)((lane << 5) + __builtin_ctz(w)) : 0xffffffffu;
    unsigned wr = w & (w - 1);
    unsigned l2 = wr ? (unsigned)((lane << 5) + __builtin_ctz(wr)) : 0xffffffffu;
    unsigned g1 = l1;
    for (int o = 32; o > 0; o >>= 1) {
      unsigned x = (unsigned)__shfl_xor((int)g1, o, 64);
      g1 = g1 < x ? g1 : x;
    }
    unsigned cand = (l1 == g1) ? l2 : l1;
    unsigned g2 = cand;
    for (int o = 32; o > 0; o >>= 1) {
      unsigned x = (unsigned)__shfl_xor((int)g2, o, 64);
      g2 = g2 < x ? g2 : x;
    }
    float2 xi = ((const float2*)xhat)[(size_t)g1 * 64 + lane];
    float2 xj = ((const float2*)xhat)[(size_t)g2 * 64 + lane];
    float d = xi.x * xj.x + xi.y * xj.y;
    for (int o = 32; o > 0; o >>= 1) d += __shfl_xor(d, o, 64);
    impv = d;
  }
  if (lane == 0) impE[k * 512 + e] = impv;
}

// ---------- dispatch 3: edge softmax + gating ----------
__device__ __forceinline__ float blockReduceSum16(float v, float* red, int t) {
  for (int o = 32; o > 0; o >>= 1) v += __shfl_xor(v, o, 64);
  __syncthreads();
  if ((t & 63) == 0) red[t >> 6] = v;
  __syncthreads();
  float s = red[0];
#pragma unroll
  for (int i = 1; i < 16; i++) s += red[i];
  return s;
}

__global__ void k_edgegate(const float* __restrict__ impE,
                           const float* __restrict__ featA, const float* __restrict__ attA,
                           const float* __restrict__ frobA, float* __restrict__ scal,
                           const int* __restrict__ epoch, float* __restrict__ out_gates,
                           float* __restrict__ egscaled, float* __restrict__ out_eg) {
  __shared__ float red[16];
  __shared__ int redi[16];
  __shared__ float imps[KCOMP];
  int k = blockIdx.x;
  int t = threadIdx.x;
  int wv0 = t >> 6, ln0 = t & 63;
  if (wv0 < KCOMP) {
    // wave wv0 reduces component wv0's partials (32 MLP blocks, 4 frob blocks)
    float pf = (ln0 < 32) ? featA[wv0 * 128 + ln0] : 0.f;
    float pa = (ln0 < 32) ? attA[wv0 * 128 + ln0] : 0.f;
    float pr = (ln0 < 4) ? frobA[wv0 * 4 + ln0] : 0.f;
    for (int o = 32; o > 0; o >>= 1) {
      pf += __shfl_xor(pf, o, 64);
      pa += __shfl_xor(pa, o, 64);
      pr += __shfl_xor(pr, o, 64);
    }
    if (ln0 == 0)
      imps[wv0] = BETA_C * sqrtf(pr) * sqrtf(pf) + (1.f - BETA_C) * (pa / (float)NN);
  }
  __syncthreads();
  float gates[KCOMP];
  float tc;
  {
    float mx = imps[0];
    for (int kk = 1; kk < KCOMP; kk++) mx = fmaxf(mx, imps[kk]);
    float ex[KCOMP], ssum = 0.f;
    for (int kk = 0; kk < KCOMP; kk++) { ex[kk] = expf(imps[kk] - mx); ssum += ex[kk]; }
    tc = TC0_C + (1.f - expf(-LAM_S * (float)epoch[0])) * (TCMAX_C - TC0_C);
    for (int kk = 0; kk < KCOMP; kk++) {
      float pi = ex[kk] / ssum;
      gates[kk] = fminf(fmaxf((pi - tc) / EPS_G + 0.5f, 0.f), 1.f);
    }
    int am = 0; float bv2 = gates[0];
    for (int kk = 1; kk < KCOMP; kk++) if (gates[kk] > bv2) { bv2 = gates[kk]; am = kk; }
    gates[am] = fmaxf(gates[am], 1.f);
  }
  if (t == 0) {
    scal[12 + k] = gates[k];
    if (k == 0) for (int kk = 0; kk < KCOMP; kk++) out_gates[kk] = gates[kk];
  }
  float imp[4];
#pragma unroll
  for (int j = 0; j < 4; j++) {
    int e = t + j * 1024;
    imp[j] = (e < MAXSE) ? impE[k * 512 + e] : 0.f;
  }
  float m = fmaxf(fmaxf(imp[0], imp[1]), fmaxf(imp[2], imp[3]));
  for (int o = 32; o > 0; o >>= 1) m = fmaxf(m, __shfl_xor(m, o, 64));
  __syncthreads();
  if ((t & 63) == 0) red[t >> 6] = m;
  __syncthreads();
  m = red[0];
#pragma unroll
  for (int i = 1; i < 16; i++) m = fmaxf(m, red[i]);
  float p[4], psum = 0.f;
#pragma unroll
  for (int j = 0; j < 4; j++) { p[j] = expf(imp[j] - m); psum += p[j]; }
  float S = blockReduceSum16(psum, red, t);
  float pi[4], tot = 0.f;
#pragma unroll
  for (int j = 0; j < 4; j++) { pi[j] = p[j] / S; tot += pi[j]; }
  float T = blockReduceSum16(tot, red, t);
  float mean = T / (float)EE;
  float devs = 0.f;
#pragma unroll
  for (int j = 0; j < 4; j++) { float d = pi[j] - mean; devs = fmaf(d, d, devs); }
  float V = blockReduceSum16(devs, red, t);
  float stdv = sqrtf(V / (float)(EE - 1));
  float theta = fminf(tc, mean + stdv);
  float eg[4], egsum = 0.f;
#pragma unroll
  for (int j = 0; j < 4; j++) {
    eg[j] = fminf(fmaxf((pi[j] - theta) / EPS_G + 0.5f, 0.f), 1.f);
    egsum += eg[j];
  }
  float EGS = blockReduceSum16(egsum, red, t);
  float bv = -1e30f; int bi = 0x7fffffff;
#pragma unroll
  for (int j = 0; j < 4; j++) if (pi[j] > bv) { bv = pi[j]; bi = t + j * 1024; }
  for (int o = 32; o > 0; o >>= 1) {
    float ov = __shfl_xor(bv, o, 64); int oi = __shfl_xor(bi, o, 64);
    if (ov > bv || (ov == bv && oi < bi)) { bv = ov; bi = oi; }
  }
  __syncthreads();
  if ((t & 63) == 0) { red[t >> 6] = bv; redi[t >> 6] = bi; }
  __syncthreads();
  float abv = red[0]; int abi = redi[0];
#pragma unroll
  for (int i = 1; i < 16; i++) {
    float ov = red[i]; int oi = redi[i];
    if (ov > abv || (ov == abv && oi < abi)) { abv = ov; abi = oi; }
  }
  float g = gates[k];
#pragma unroll
  for (int j = 0; j < 4; j++) {
    int e = t + j * 1024;
    float egv = eg[j];
    if (EGS < 1.f && e == abi) egv = 1.f;
    out_eg[(size_t)k * EE + e] = egv;
    float eff = (g > 0.5f) ? egv : 1.f;
    egscaled[k * EE + e] = g * eff;
  }
}

// ---------- dispatch 4: Hp row compose directly in global (no LDS row) + rowscan ----------
__global__ void k_hprow(const unsigned* __restrict__ emask,
                        const int* __restrict__ ncnt, const unsigned short* __restrict__ nelist,
                        const float* __restrict__ egs, const float* __restrict__ scal,
                        const float* __restrict__ xhat, const float* __restrict__ xnorm,
                        float* __restrict__ out, float* __restrict__ z) {
  __shared__ unsigned short elds[MAXNE];
  __shared__ float evals[MAXNE];
  __shared__ unsigned wpart[4][64];
  __shared__ unsigned short list[2048];
  __shared__ int cnt_s;
  __shared__ float sred[4];
  int k = blockIdx.y, n = blockIdx.x, t = threadIdx.x;
  float g = scal[12 + k];
  float* orow = out + ((size_t)(k * NN + n)) * EE;
  vf4* o4 = (vf4*)orow;
  vf4 z4 = {0.f, 0.f, 0.f, 0.f};
  if (g <= 0.f) {
#pragma unroll
    for (int i = 0; i < 4; i++) __builtin_nontemporal_store(z4, &o4[t + i * 256]);
    if (t == 0) z[k * NN + n] = 0.f;
    return;
  }
  int ec = ncnt[k * NN + n]; if (ec > MAXNE) ec = MAXNE;
  if (t == 0) cnt_s = 0;
  if (t < ec) {
    int e = nelist[((size_t)(k * NN + n)) * MAXNE + t];
    elds[t] = (unsigned short)e;
    evals[t] = egs[k * EE + e];
  }
  // zero the full output row straight to global (write-once data, nt)
#pragma unroll
  for (int i = 0; i < 4; i++) __builtin_nontemporal_store(z4, &o4[t + i * 256]);
  __syncthreads();   // drains vmcnt: zeros globally ordered before scatter below
  if (t < ec) orow[elds[t]] = evals[t];
  // ---- rowscan (uses evals in LDS; no row buffer needed) ----
  int lane = t & 63, wv = t >> 6;
  unsigned acc = 0;
  for (int it = wv; it < ec; it += 4) {
    if (evals[it] > 0.f) acc |= emask[((size_t)(k * EE) + elds[it]) * 64 + lane];
  }
  wpart[wv][lane] = acc;
  __syncthreads();
  if (t < 64) {
    unsigned w = wpart[0][t] | wpart[1][t] | wpart[2][t] | wpart[3][t];
    if (t == (n >> 5)) w &= ~(1u << (n & 31));
    int c = __popc(w);
    if (c > 0) {
      int base = atomicAdd(&cnt_s, c);
      while (w) {
        int b = __builtin_ctz(w); w &= w - 1;
        list[base++] = (unsigned short)((t << 5) + b);
      }
    }
  }
  __syncthreads();
  int cnt = cnt_s;
  if (cnt == 0) { if (t == 0) z[k * NN + n] = 0.f; return; }
  int fc = lane & 31, hh = lane >> 5;
  float4 xn4 = ((const float4*)xhat)[(size_t)n * 32 + fc];
  float a = 0.f;
#pragma unroll 4
  for (int it = wv * 2 + hh; it < cnt; it += 8) {
    int m = (int)list[it];
    float4 xm = ((const float4*)xhat)[(size_t)m * 32 + fc];
    a += xn4.x * xm.x + xn4.y * xm.y + xn4.z * xm.z + xn4.w * xm.w;
  }
  for (int o = 32; o > 0; o >>= 1) a += __shfl_xor(a, o, 64);
  if (lane == 0) sred[wv] = a;
  __syncthreads();
  if (t == 0) {
    float s = sred[0] + sred[1] + sred[2] + sred[3];
    z[k * NN + n] = (s / (float)cnt) * xnorm[n];
  }
}

// ---------- dispatch 5: npi = softmax(z) per k ----------
__global__ void k_npi(const float* __restrict__ z, float* __restrict__ out_npi) {
  __shared__ float red[4];
  int k = blockIdx.x, t = threadIdx.x;
  float v[8]; float m = -1e30f;
#pragma unroll
  for (int j = 0; j < 8; j++) { v[j] = z[k * NN + t + j * 256]; m = fmaxf(m, v[j]); }
  for (int o = 32; o > 0; o >>= 1) m = fmaxf(m, __shfl_xor(m, o, 64));
  if ((t & 63) == 0) red[t >> 6] = m;
  __syncthreads();
  m = fmaxf(fmaxf(red[0], red[1]), fmaxf(red[2], red[3]));
  __syncthreads();
  float pe[8]; float s = 0.f;
#pragma unroll
  for (int j = 0; j < 8; j++) { pe[j] = expf(v[j] - m); s += pe[j]; }
  for (int o = 32; o > 0; o >>= 1) s += __shfl_xor(s, o, 64);
  if ((t & 63) == 0) red[t >> 6] = s;
  __syncthreads();
  s = red[0] + red[1] + red[2] + red[3];
#pragma unroll
  for (int j = 0; j < 8; j++) out_npi[k * NN + t + j * 256] = pe[j] / s;
}

extern "C" void kernel_launch(void* const* d_in, const int* in_sizes, int n_in,
                              void* d_out, int out_size, void* d_ws, size_t ws_size,
                              hipStream_t stream) {
  const float* H     = (const float*)d_in[0];
  const float* X     = (const float*)d_in[1];
  const int*   epoch = (const int*)d_in[2];
  const float* w1    = (const float*)d_in[3];
  const float* b1    = (const float*)d_in[4];
  const float* w2    = (const float*)d_in[5];
  const float* b2    = (const float*)d_in[6];
  const float* compW = (const float*)d_in[7];
  const float* aw1   = (const float*)d_in[8];
  const float* ab1   = (const float*)d_in[9];
  const float* aw2   = (const float*)d_in[10];
  const float* ab2   = (const float*)d_in[11];

  char* ws = (char*)d_ws;
  float* xhat  = (float*)(ws + OFF_XHAT);
  float* xnorm = (float*)(ws + OFF_XNORM);
  float* scal  = (float*)(ws + OFF_SCAL);
  int*   ncnt  = (int*)(ws + OFF_NCNT);
  unsigned* emask = (unsigned*)(ws + OFF_EMASK);
  unsigned short* nelist = (unsigned short*)(ws + OFF_NELIST);
  float* impE  = (float*)(ws + OFF_IMPE);
  float* egs   = (float*)(ws + OFF_EGS);
  float* zbuf  = (float*)(ws + OFF_Z);
  float* featA = (float*)(ws + OFF_FEAT);
  float* attA  = (float*)(ws + OFF_ATT);
  float* frobA = (float*)(ws + OFF_FROB);

  float* out       = (float*)d_out;
  float* out_gates = out + (size_t)KCOMP * NN * EE;
  float* out_eg    = out_gates + KCOMP;
  float* out_npi   = out_eg + (size_t)KCOMP * EE;

  hipMemsetAsync(ncnt, 0, (size_t)KCOMP * NN * sizeof(int), stream);
  k_d1<<<528, 1024, 0, stream>>>((const float4*)H, emask, X, xhat, xnorm,
                                 w1, b1, w2, b2, aw1, ab1, aw2, ab2,
                                 (const float4*)compW, ncnt, nelist, featA, attA, frobA);
  k_d2<<<dim3(125, KCOMP), 256, 0, stream>>>(emask, xhat, impE);
  k_edgegate<<<KCOMP, 1024, 0, stream>>>(impE, featA, attA, frobA, scal, epoch,
                                         out_gates, egs, out_eg);
  k_hprow<<<dim3(NN, KCOMP), 256, 0, stream>>>(emask, ncnt, nelist, egs, scal, xhat, xnorm,
                                               out, zbuf);
  k_npi<<<KCOMP, 256, 0, stream>>>(zbuf, out_npi);
}